// Round 1
// baseline (552.138 us; speedup 1.0000x reference)
//
#include <hip/hip_runtime.h>

#define C_IN    256
#define S_CELLS 90
#define A_OUT   2086
#define K_FC    180      // E * S = 2*90
#define K_PAD   192      // K padded to 6*32 for mfma 16x16x32
#define N_PAD   2176     // 17 * 128
#define B_BATCH 4096

typedef __attribute__((ext_vector_type(8))) short short8;   // 8 bf16 = 4 VGPR
typedef __attribute__((ext_vector_type(4))) float floatx4;  // mfma C/D

static __device__ __forceinline__ unsigned short f2bf(float f) {
    // round-to-nearest-even fp32 -> bf16 (inputs are finite)
    unsigned u = __float_as_uint(f);
    return (unsigned short)((u + 0x7FFFu + ((u >> 16) & 1u)) >> 16);
}

// ---------------------------------------------------------------------------
// Kernel A: 1x1 conv + BN + 2-head attention (head_dim=1) + out_proj
//   -> Abf [B, 192] bf16 (j = e*90 + s; j in [180,192) zero pad)
// R4: one WAVE per batch. Lanes 0..44 each own the s-pair (2l, 2l+1) and
// load float2 (8 B/lane): one wave-load = one contiguous 360 B channel row
// of x -> full coalescing at the 8-16 B/lane sweet spot (G13), vs the old
// 4 B/lane scalar loads. 512-thread blocks = 8 batches/block.
// ---------------------------------------------------------------------------
__global__ __launch_bounds__(512) void front_kernel(
    const float* __restrict__ x,        // [B,256,90]
    const float* __restrict__ conv_w,   // [2,256]
    const float* __restrict__ bn_gamma,
    const float* __restrict__ bn_beta,
    const float* __restrict__ bn_mean,
    const float* __restrict__ bn_var,
    const float* __restrict__ ipw,      // [6,2]
    const float* __restrict__ ipb,      // [6]
    const float* __restrict__ opw,      // [2,2]
    const float* __restrict__ opb,      // [2]
    unsigned short* __restrict__ Abf)   // [B,192] bf16
{
    __shared__ float4 kvs[8][S_CELLS];   // (k0, v0, k1, v1) per cell, per wave

    const int wid  = threadIdx.x >> 6;   // wave id = sub-batch 0..7
    const int lane = threadIdx.x & 63;
    const int b    = blockIdx.x * 8 + wid;

    float qA0 = 0.f, qA1 = 0.f, qB0 = 0.f, qB1 = 0.f;
    const int sA = 2 * lane;             // cells owned by this lane
    const int sB = 2 * lane + 1;

    if (lane < 45) {
        // conv over channels: per c, 45 lanes x float2 = the whole 90-float row
        const float2* xb2 = reinterpret_cast<const float2*>(
                                x + (size_t)b * (C_IN * S_CELLS)) + lane;
        float a00 = 0.f, a01 = 0.f, a10 = 0.f, a11 = 0.f;  // a[ch][cell]
        #pragma unroll 8
        for (int c = 0; c < C_IN; ++c) {
            const float2 v = xb2[c * 45];
            const float w0 = conv_w[c];
            const float w1 = conv_w[C_IN + c];
            a00 = fmaf(w0, v.x, a00); a01 = fmaf(w0, v.y, a01);
            a10 = fmaf(w1, v.x, a10); a11 = fmaf(w1, v.y, a11);
        }
        const float sc0 = bn_gamma[0] * rsqrtf(bn_var[0] + 1e-5f);
        const float sc1 = bn_gamma[1] * rsqrtf(bn_var[1] + 1e-5f);
        const float sh0 = bn_beta[0] - bn_mean[0] * sc0;
        const float sh1 = bn_beta[1] - bn_mean[1] * sc1;
        const float yA0 = a00 * sc0 + sh0, yA1 = a10 * sc1 + sh1;
        const float yB0 = a01 * sc0 + sh0, yB1 = a11 * sc1 + sh1;

        qA0 = ipw[0] * yA0 + ipw[1] * yA1 + ipb[0];
        qA1 = ipw[2] * yA0 + ipw[3] * yA1 + ipb[1];
        qB0 = ipw[0] * yB0 + ipw[1] * yB1 + ipb[0];
        qB1 = ipw[2] * yB0 + ipw[3] * yB1 + ipb[1];

        kvs[wid][sA] = make_float4(
            ipw[4] * yA0 + ipw[5]  * yA1 + ipb[2],   // k0
            ipw[8] * yA0 + ipw[9]  * yA1 + ipb[4],   // v0
            ipw[6] * yA0 + ipw[7]  * yA1 + ipb[3],   // k1
            ipw[10]* yA0 + ipw[11] * yA1 + ipb[5]);  // v1
        kvs[wid][sB] = make_float4(
            ipw[4] * yB0 + ipw[5]  * yB1 + ipb[2],
            ipw[8] * yB0 + ipw[9]  * yB1 + ipb[4],
            ipw[6] * yB0 + ipw[7]  * yB1 + ipb[3],
            ipw[10]* yB0 + ipw[11] * yB1 + ipb[5]);
    }
    __syncthreads();

    if (lane < 45) {
        float dA0 = 0.f, nA0 = 0.f, dA1 = 0.f, nA1 = 0.f;
        float dB0 = 0.f, nB0 = 0.f, dB1 = 0.f, nB1 = 0.f;
        #pragma unroll 5
        for (int j = 0; j < S_CELLS; ++j) {
            const float4 kv = kvs[wid][j];     // broadcast read, conflict-free
            float e;
            e = __expf(qA0 * kv.x); dA0 += e; nA0 = fmaf(e, kv.y, nA0);
            e = __expf(qA1 * kv.z); dA1 += e; nA1 = fmaf(e, kv.w, nA1);
            e = __expf(qB0 * kv.x); dB0 += e; nB0 = fmaf(e, kv.y, nB0);
            e = __expf(qB1 * kv.z); dB1 += e; nB1 = fmaf(e, kv.w, nB1);
        }
        const float oA0 = nA0 / dA0, oA1 = nA1 / dA1;
        const float oB0 = nB0 / dB0, oB1 = nB1 / dB1;
        unsigned short* ab = Abf + (size_t)b * K_PAD;
        ab[sA]           = f2bf(opw[0] * oA0 + opw[1] * oA1 + opb[0]);
        ab[S_CELLS + sA] = f2bf(opw[2] * oA0 + opw[3] * oA1 + opb[1]);
        ab[sB]           = f2bf(opw[0] * oB0 + opw[1] * oB1 + opb[0]);
        ab[S_CELLS + sB] = f2bf(opw[2] * oB0 + opw[3] * oB1 + opb[1]);
    } else if (lane < 57) {
        // lanes 45..56 zero the K pad (j = 180..191)
        Abf[(size_t)b * K_PAD + 135 + lane] = 0;
    }
}

// ---------------------------------------------------------------------------
// Kernel B: bf16 MFMA GEMM. out[m][n] = sum_k Abf[m][k]*W[n][k] + bias[n]
// M=4096, N=2176(pad), K=192. Block 128x128, 256 thr = 4 waves in 2x2 of
// 64x64 wave-tiles; mfma_f32_16x16x32_bf16, BK=64 (2 k-steps/stage).
// LDS rows padded 64->72 bf16 (+16B): row stride 144 B = 36 banks -> frag
// reads land 2-way (free, m136) instead of 16-way.
// R4: wconv_kernel folded in — W is read as fp32 (rows 720 B = 16B-aligned,
// so two float4 loads per 8-elem chunk) and converted to bf16 during LDS
// staging. W is 1.5 MB -> L2-resident across all 32 row-blocks, so the
// 32x fp32 re-read costs L2 BW only; saves the wconv launch + Wbf round trip.
// ---------------------------------------------------------------------------
#define BM 128
#define BN 128
#define BK 64
#define LDSROW 72

__global__ __launch_bounds__(256) void fc_mfma_kernel(
    const unsigned short* __restrict__ Abf,  // [4096,192] bf16
    const float* __restrict__ W,             // [2086,180] fp32
    const float* __restrict__ bias,          // [2086]
    float* __restrict__ out)                 // [4096,2086] fp32
{
    __shared__ __align__(16) unsigned short As[BM * LDSROW];
    __shared__ __align__(16) unsigned short Bs[BN * LDSROW];

    const int tid  = threadIdx.x;
    const int lane = tid & 63;
    const int wave = tid >> 6;
    const int wy   = wave >> 1;          // M half (0/1)
    const int wx   = wave & 1;           // N half (0/1)
    const int lrow = lane & 15;
    const int lk   = (lane >> 4) * 8;    // k-offset within a 32-k step
    const int bm   = blockIdx.y * BM;
    const int bn   = blockIdx.x * BN;

    floatx4 acc[4][4] = {};

    for (int k0 = 0; k0 < K_PAD; k0 += BK) {
        // stage: 128 rows x 64 bf16 = 128 rows x 8 chunks per operand,
        // 2048 chunks total / 256 threads = 8 per thread
        for (int q = tid; q < BM * 8; q += 256) {
            const int m = q >> 3, c = q & 7;
            *(int4*)&As[m * LDSROW + c * 8] =
                *(const int4*)(Abf + (size_t)(bm + m) * K_PAD + k0 + c * 8);

            const int n  = bn + m;
            const int kb = k0 + c * 8;
            unsigned short h[8];
            if (n < A_OUT && kb + 7 < K_FC) {
                const float4 f0 = *(const float4*)(W + (size_t)n * K_FC + kb);
                const float4 f1 = *(const float4*)(W + (size_t)n * K_FC + kb + 4);
                h[0] = f2bf(f0.x); h[1] = f2bf(f0.y); h[2] = f2bf(f0.z); h[3] = f2bf(f0.w);
                h[4] = f2bf(f1.x); h[5] = f2bf(f1.y); h[6] = f2bf(f1.z); h[7] = f2bf(f1.w);
            } else {
                #pragma unroll
                for (int t = 0; t < 8; ++t) {
                    const int k = kb + t;
                    h[t] = (n < A_OUT && k < K_FC)
                           ? f2bf(W[(size_t)n * K_FC + k]) : (unsigned short)0;
                }
            }
            *(int4*)&Bs[m * LDSROW + c * 8] = *(const int4*)h;
        }
        __syncthreads();

        #pragma unroll
        for (int ks = 0; ks < 2; ++ks) {
            short8 af[4], bf[4];
            #pragma unroll
            for (int t = 0; t < 4; ++t) {
                af[t] = *(const short8*)&As[(wy * 64 + t * 16 + lrow) * LDSROW + ks * 32 + lk];
                bf[t] = *(const short8*)&Bs[(wx * 64 + t * 16 + lrow) * LDSROW + ks * 32 + lk];
            }
            #pragma unroll
            for (int mt = 0; mt < 4; ++mt)
                #pragma unroll
                for (int nt = 0; nt < 4; ++nt)
                    acc[mt][nt] = __builtin_amdgcn_mfma_f32_16x16x32_bf16(
                        af[mt], bf[nt], acc[mt][nt], 0, 0, 0);
        }
        __syncthreads();
    }

    // epilogue: C/D layout col=lane&15, row=(lane>>4)*4+r  [m89]
    const int ccol = lane & 15;
    const int crow = (lane >> 4) * 4;
    #pragma unroll
    for (int mt = 0; mt < 4; ++mt) {
        #pragma unroll
        for (int nt = 0; nt < 4; ++nt) {
            const int n_out = bn + wx * 64 + nt * 16 + ccol;
            if (n_out >= A_OUT) continue;
            const int m_base = bm + wy * 64 + mt * 16 + crow;
            const float bv = bias[n_out];
            #pragma unroll
            for (int r = 0; r < 4; ++r)
                out[(size_t)(m_base + r) * A_OUT + n_out] = acc[mt][nt][r] + bv;
        }
    }
}

// ---------------------------------------------------------------------------
extern "C" void kernel_launch(void* const* d_in, const int* in_sizes, int n_in,
                              void* d_out, int out_size, void* d_ws, size_t ws_size,
                              hipStream_t stream) {
    const float* x        = (const float*)d_in[0];
    const float* conv_w   = (const float*)d_in[1];
    const float* bn_gamma = (const float*)d_in[2];
    const float* bn_beta  = (const float*)d_in[3];
    const float* bn_mean  = (const float*)d_in[4];
    const float* bn_var   = (const float*)d_in[5];
    const float* ipw      = (const float*)d_in[6];
    const float* ipb      = (const float*)d_in[7];
    const float* opw      = (const float*)d_in[8];
    const float* opb      = (const float*)d_in[9];
    const float* fc_w     = (const float*)d_in[10];
    const float* fc_b     = (const float*)d_in[11];
    float* out = (float*)d_out;

    unsigned short* Abf = (unsigned short*)d_ws;   // 4096*192*2 = 1.57 MB

    front_kernel<<<dim3(B_BATCH / 8), 512, 0, stream>>>(
        x, conv_w, bn_gamma, bn_beta, bn_mean, bn_var,
        ipw, ipb, opw, opb, Abf);

    fc_mfma_kernel<<<dim3(N_PAD / BN, B_BATCH / BM), 256, 0, stream>>>(
        Abf, fc_w, fc_b, out);
}